// Round 1
// baseline (443.370 us; speedup 1.0000x reference)
//
#include <hip/hip_runtime.h>
#include <cstdint>
#include <cstddef>

typedef __bf16  bf16x8 __attribute__((ext_vector_type(8)));
typedef float   f32x4  __attribute__((ext_vector_type(4)));
typedef unsigned short u16x8 __attribute__((ext_vector_type(8)));
typedef unsigned short u16x4 __attribute__((ext_vector_type(4)));

#define B_SZ  4096
#define SEQ   9
#define CDIM  768
#define HEADS 12
#define DH    64
#define MROWS (B_SZ*SEQ)      // 36864
#define NQKV  (3*CDIM)        // 2304
#define NPAIR (B_SZ*HEADS)    // 49152
#define PPB   28              // (b,h) pairs per 256-thread block in attention

__device__ inline float b2f(unsigned short u){
  union{unsigned i; float f;} x; x.i = ((unsigned)u)<<16; return x.f;
}
__device__ inline unsigned short f2b(float f){ // RNE fp32->bf16
  unsigned x = __float_as_uint(f);
  return (unsigned short)((x + 0x7fffu + ((x>>16)&1u)) >> 16);
}

// ---------------- K0a: fp32 -> bf16, vectorized ----------------
__global__ __launch_bounds__(256) void k_conv(const float* __restrict__ in,
                                              unsigned short* __restrict__ out){
  int t = blockIdx.x*256 + threadIdx.x;
  float4 v = ((const float4*)in)[t];
  u16x4 o; o.x=f2b(v.x); o.y=f2b(v.y); o.z=f2b(v.z); o.w=f2b(v.w);
  ((u16x4*)out)[t] = o;
}

// ------- K0b: transpose+convert: in fp32 [R][C] -> out bf16 [C][R] -------
__global__ __launch_bounds__(256) void k_tconv(const float* __restrict__ in,
                                               unsigned short* __restrict__ out,
                                               int R, int C){
  int t = blockIdx.x*256 + threadIdx.x;   // output-linear: coalesced writes
  int c = t / R, r = t - c*R;
  out[t] = f2b(in[(size_t)r*C + c]);
}

// ---------------- K0c: dRoFE cos/sin table [9][64] ----------------
__global__ void k_table(float* __restrict__ cs, float* __restrict__ sn){
  int t = threadIdx.x;
  if (t >= SEQ*DH) return;
  const float blo[9] = {1.f,4.f,8.f,10.f,12.f,30.f,1.f,8.f,1.f};
  const float bhi[9] = {4.f,8.f,10.f,12.f,30.f,45.f,8.f,30.f,45.f};
  int n = t / DH, d = t - n*DH;
  int f = (d < 32) ? (d>>1) : ((d-32)>>1);
  float freq = 3.14159265358979f * (1.0f + (4.0f/15.0f)*(float)f); // pi*linspace(1,5,16)
  float band = (d < 32) ? blo[n] : bhi[n];
  float ang = band * freq;
  cs[t] = cosf(ang);
  sn[t] = sinf(ang);
}

// ---------------- GEMM: C[M][N] = A[M][K] * Bt[N][K]^T ----------------
// m97 structure: 128x128 tile, BK=32, 4 waves (2x2), global_load_lds width 16.
template<int WRITE_F32>
__global__ __launch_bounds__(256) void k_gemm_bt(const unsigned short* __restrict__ A,
                                                 const unsigned short* __restrict__ Bt,
                                                 void* __restrict__ Cout,
                                                 const float* __restrict__ bias,
                                                 int M, int N, int K, int NT){
  __shared__ unsigned short As[128*32];
  __shared__ unsigned short Bs[128*32];
  int bx = blockIdx.x;
  int bm = bx / NT, bn = bx - bm*NT;
  int m0 = bm*128, n0 = bn*128;
  int tid = threadIdx.x;
  int lane = tid & 63, w = tid >> 6;
  int wr = w >> 1, wc = w & 1;
  int rowL = lane >> 2;          // 0..15 within 16-row staging group
  int kk   = (lane & 3) * 8;     // k-octet within BK=32
  int r = lane & 15, g = lane >> 4;

  const f32x4 fzero = {0.f,0.f,0.f,0.f};
  f32x4 acc[4][4];
  #pragma unroll
  for (int mi=0;mi<4;++mi)
    #pragma unroll
    for (int ni=0;ni<4;++ni) acc[mi][ni] = fzero;

  int KT = K >> 5;
  for (int kt=0; kt<KT; ++kt){
    int k0 = kt << 5;
    #pragma unroll
    for (int is=0; is<2; ++is){
      int rb = w*16 + is*64;   // wave-uniform
      const unsigned short* ga = A  + (size_t)(m0 + rb + rowL)*K + k0 + kk;
      const unsigned short* gb = Bt + (size_t)(n0 + rb + rowL)*K + k0 + kk;
      __builtin_amdgcn_global_load_lds((const __attribute__((address_space(1))) void*)ga,
          (__attribute__((address_space(3))) void*)(&As[rb*32]), 16, 0, 0);
      __builtin_amdgcn_global_load_lds((const __attribute__((address_space(1))) void*)gb,
          (__attribute__((address_space(3))) void*)(&Bs[rb*32]), 16, 0, 0);
    }
    __syncthreads();
    bf16x8 av[4], bv[4];
    #pragma unroll
    for (int mi=0;mi<4;++mi)
      av[mi] = *reinterpret_cast<const bf16x8*>(&As[(wr*64 + mi*16 + r)*32 + g*8]);
    #pragma unroll
    for (int ni=0;ni<4;++ni)
      bv[ni] = *reinterpret_cast<const bf16x8*>(&Bs[(wc*64 + ni*16 + r)*32 + g*8]);
    #pragma unroll
    for (int mi=0;mi<4;++mi)
      #pragma unroll
      for (int ni=0;ni<4;++ni)
        acc[mi][ni] = __builtin_amdgcn_mfma_f32_16x16x32_bf16(av[mi], bv[ni], acc[mi][ni], 0, 0, 0);
    __syncthreads();
  }

  // C/D layout (verified m89/m91): col = lane&15, row = (lane>>4)*4 + reg
  #pragma unroll
  for (int mi=0;mi<4;++mi){
    #pragma unroll
    for (int ni=0;ni<4;++ni){
      int col = n0 + wc*64 + ni*16 + r;
      float bv2 = WRITE_F32 ? (bias ? bias[col] : 0.f) : 0.f;
      #pragma unroll
      for (int q=0;q<4;++q){
        int row = m0 + wr*64 + mi*16 + g*4 + q;
        float val = acc[mi][ni][q];
        if (WRITE_F32) ((float*)Cout)[(size_t)row*N + col] = val + bv2;
        else ((unsigned short*)Cout)[(size_t)row*N + col] = f2b(val);
      }
    }
  }
}

// ---------------- dRoFE + attention ----------------
// thread = (pair, i-row). qkv row layout: [q(0..767) | k(768..1535) | v(1536..2303)]
__global__ __launch_bounds__(256) void k_attn(const unsigned short* __restrict__ qkv,
                                              const float* __restrict__ demo,
                                              const float* __restrict__ cs,
                                              const float* __restrict__ sn,
                                              unsigned short* __restrict__ out){
  __shared__ float s_cs[SEQ*DH], s_sn[SEQ*DH];
  int tid = threadIdx.x;
  for (int t=tid; t<SEQ*DH; t+=256){ s_cs[t]=cs[t]; s_sn[t]=sn[t]; }
  __syncthreads();

  int pr = tid / 9, i = tid - pr*9;
  int pair = blockIdx.x*PPB + pr;
  if (pr >= PPB || pair >= NPAIR) return;
  int b = pair / HEADS, h = pair - b*HEADS;
  float age = demo[2*b], gen = demo[2*b+1];
  const unsigned short* base = qkv + (size_t)b*SEQ*NQKV + h*DH;

  // q row i, roped:  q' = age*q*cos + gen*rot(q)*sin ; rot=(-x1,x0) pairs
  float qr[64];
  {
    const u16x8* qp = (const u16x8*)(base + (size_t)i*NQKV);
    #pragma unroll
    for (int t8=0;t8<8;++t8){
      u16x8 v = qp[t8];
      #pragma unroll
      for (int e=0;e<8;e+=2){
        int d = t8*8+e;
        float x0=b2f(v[e]), x1=b2f(v[e+1]);
        qr[d]   = age*x0*s_cs[i*64+d]   - gen*x1*s_sn[i*64+d];
        qr[d+1] = age*x1*s_cs[i*64+d+1] + gen*x0*s_sn[i*64+d+1];
      }
    }
  }

  float s[9]; float mx = -1e30f;
  #pragma unroll
  for (int j=0;j<9;++j){
    const u16x8* kp = (const u16x8*)(base + (size_t)j*NQKV + CDIM);
    float acc = 0.f;
    #pragma unroll
    for (int t8=0;t8<8;++t8){
      u16x8 v = kp[t8];
      #pragma unroll
      for (int e=0;e<8;e+=2){
        int d = t8*8+e;
        float x0=b2f(v[e]), x1=b2f(v[e+1]);
        float k0 = age*x0*s_cs[j*64+d]   - gen*x1*s_sn[j*64+d];
        float k1 = age*x1*s_cs[j*64+d+1] + gen*x0*s_sn[j*64+d+1];
        acc += qr[d]*k0 + qr[d+1]*k1;
      }
    }
    s[j] = acc * 0.125f;           // D^-0.5
    mx = fmaxf(mx, s[j]);
  }
  float den = 0.f;
  #pragma unroll
  for (int j=0;j<9;++j){ s[j] = __expf(s[j]-mx); den += s[j]; }
  float inv = 1.f/den;

  float o[64];
  #pragma unroll
  for (int d=0;d<64;++d) o[d]=0.f;
  #pragma unroll
  for (int j=0;j<9;++j){
    float p = s[j]*inv;
    const u16x8* vp = (const u16x8*)(base + (size_t)j*NQKV + 2*CDIM);
    #pragma unroll
    for (int t8=0;t8<8;++t8){
      u16x8 v = vp[t8];
      #pragma unroll
      for (int e=0;e<8;++e) o[t8*8+e] += p*b2f(v[e]);
    }
  }

  u16x8* op = (u16x8*)(out + (size_t)(b*SEQ+i)*CDIM + h*DH);
  #pragma unroll
  for (int t8=0;t8<8;++t8){
    u16x8 v;
    #pragma unroll
    for (int e=0;e<8;++e) v[e]=f2b(o[t8*8+e]);
    op[t8]=v;
  }
}

extern "C" void kernel_launch(void* const* d_in, const int* in_sizes, int n_in,
                              void* d_out, int out_size, void* d_ws, size_t ws_size,
                              hipStream_t stream){
  const float* x    = (const float*)d_in[0];
  const float* demo = (const float*)d_in[1];
  const float* Wq   = (const float*)d_in[2];
  const float* Wp   = (const float*)d_in[3];
  const float* bp   = (const float*)d_in[4];
  float* outp = (float*)d_out;

  char* wsb = (char*)d_ws;
  // layout (bytes): [xb: 56,623,104][Wq_t: 3,538,944][Wp_t: 1,179,648][cs/sn: 4,608][qkv: 169,869,312]
  unsigned short* xb   = (unsigned short*)wsb;              // x bf16; later reused as attn output
  unsigned short* Wq_t = (unsigned short*)(wsb + 56623104); // [2304][768]
  unsigned short* Wp_t = (unsigned short*)(wsb + 60162048); // [768][768]
  float* cs = (float*)(wsb + 61341696);
  float* sn = cs + SEQ*DH;
  unsigned short* qkv  = (unsigned short*)(wsb + 61346304); // [36864][2304] bf16

  k_conv <<< MROWS*CDIM/1024, 256, 0, stream >>> (x, xb);
  k_tconv<<< CDIM*NQKV/256,  256, 0, stream >>> (Wq, Wq_t, CDIM, NQKV);
  k_tconv<<< CDIM*CDIM/256,  256, 0, stream >>> (Wp, Wp_t, CDIM, CDIM);
  k_table<<< 1, 576, 0, stream >>> (cs, sn);

  k_gemm_bt<0><<< (MROWS/128)*(NQKV/128), 256, 0, stream >>>
      (xb, Wq_t, qkv, nullptr, MROWS, NQKV, CDIM, NQKV/128);

  k_attn <<< (NPAIR + PPB - 1)/PPB, 256, 0, stream >>> (qkv, demo, cs, sn, xb);

  k_gemm_bt<1><<< (MROWS/128)*(CDIM/128), 256, 0, stream >>>
      (xb, Wp_t, outp, bp, MROWS, CDIM, CDIM, CDIM/128);
}

// Round 2
// 397.453 us; speedup vs baseline: 1.1155x; 1.1155x over previous
//
#include <hip/hip_runtime.h>
#include <cstdint>
#include <cstddef>

typedef __bf16  bf16x8 __attribute__((ext_vector_type(8)));
typedef float   f32x4  __attribute__((ext_vector_type(4)));
typedef unsigned short u16x8 __attribute__((ext_vector_type(8)));
typedef unsigned short u16x4 __attribute__((ext_vector_type(4)));

#define B_SZ  4096
#define SEQ   9
#define CDIM  768
#define HEADS 12
#define DH    64
#define MROWS (B_SZ*SEQ)      // 36864
#define NQKV  (3*CDIM)        // 2304
#define NPAIR (B_SZ*HEADS)    // 49152
#define PPB   28
#define GK    768             // K for both GEMMs
#define NTK   12              // K-tiles (GK/64)

#define AS1 __attribute__((address_space(1)))
#define AS3 __attribute__((address_space(3)))

__device__ inline float b2f(unsigned short u){
  union{unsigned i; float f;} x; x.i = ((unsigned)u)<<16; return x.f;
}
__device__ inline unsigned short f2b(float f){ // RNE fp32->bf16
  unsigned x = __float_as_uint(f);
  return (unsigned short)((x + 0x7fffu + ((x>>16)&1u)) >> 16);
}

// ---------------- K0a: fp32 -> bf16, vectorized ----------------
__global__ __launch_bounds__(256) void k_conv(const float* __restrict__ in,
                                              unsigned short* __restrict__ out){
  int t = blockIdx.x*256 + threadIdx.x;
  float4 v = ((const float4*)in)[t];
  u16x4 o; o.x=f2b(v.x); o.y=f2b(v.y); o.z=f2b(v.z); o.w=f2b(v.w);
  ((u16x4*)out)[t] = o;
}

// ------- K0b: transpose+convert: in fp32 [R][C] -> out bf16 [C][R] -------
__global__ __launch_bounds__(256) void k_tconv(const float* __restrict__ in,
                                               unsigned short* __restrict__ out,
                                               int R, int C){
  int t = blockIdx.x*256 + threadIdx.x;
  int c = t / R, r = t - c*R;
  out[t] = f2b(in[(size_t)r*C + c]);
}

// ---------------- K0c: dRoFE cos/sin table [9][64] ----------------
__global__ void k_table(float* __restrict__ cs, float* __restrict__ sn){
  int t = threadIdx.x;
  if (t >= SEQ*DH) return;
  const float blo[9] = {1.f,4.f,8.f,10.f,12.f,30.f,1.f,8.f,1.f};
  const float bhi[9] = {4.f,8.f,10.f,12.f,30.f,45.f,8.f,30.f,45.f};
  int n = t / DH, d = t - n*DH;
  int f = (d < 32) ? (d>>1) : ((d-32)>>1);
  float freq = 3.14159265358979f * (1.0f + (4.0f/15.0f)*(float)f);
  float band = (d < 32) ? blo[n] : bhi[n];
  float ang = band * freq;
  cs[t] = cosf(ang);
  sn[t] = sinf(ang);
}

// ================= 256x256 8-phase GEMM (T2+T3+T4+T5) =================
// C[M][N] = A[M][GK] * Bt[N][GK]^T.  512 thr (8 waves 2Mx4N), BK=64 staged
// as two K-halves; per-matrix 4-slot ring (2dbuf x 2half), 128 KiB LDS.
// LDS swizzle: 16B segment s = g ^ (r&3) ^ ((r>>2)&3)  (<=2-way, free).
#define GLOAD(SRC, LDSOFF) \
  __builtin_amdgcn_global_load_lds((const AS1 void*)(SRC), \
      (AS3 void*)(smem + (LDSOFF) + (w<<10)), 16, 0, 0)

#define PHASE_MID  do{ __builtin_amdgcn_s_barrier(); \
  asm volatile("s_waitcnt lgkmcnt(0)" ::: "memory"); \
  __builtin_amdgcn_sched_barrier(0); \
  __builtin_amdgcn_s_setprio(1); }while(0)
#define PHASE_END  do{ __builtin_amdgcn_s_setprio(0); \
  __builtin_amdgcn_s_barrier(); }while(0)

#define MFMA8x2(NA, NB) do{ \
  _Pragma("unroll") \
  for (int mi=0;mi<8;++mi){ \
    acc[mi][NA] = __builtin_amdgcn_mfma_f32_16x16x32_bf16(aR[mi], bRa, acc[mi][NA], 0,0,0); \
    acc[mi][NB] = __builtin_amdgcn_mfma_f32_16x16x32_bf16(aR[mi], bRb, acc[mi][NB], 0,0,0); } }while(0)

// One K-tile = 4 phases. DB is compile-time (0 or 2).
#define TILE_BODY(T, DB) do{ \
  const char* aS0 = smem + (DB)*16384; \
  const char* aS1 = smem + ((DB)+1)*16384; \
  const char* bS0 = smem + 65536 + (DB)*16384; \
  const char* bS1 = smem + 65536 + ((DB)+1)*16384; \
  int u1=(T)+1; if(u1>NTK-1)u1=NTK-1; int u2=(T)+2; if(u2>NTK-1)u2=NTK-1; \
  size_t o1=(size_t)u1*64+32, o2a=(size_t)u2*64, o2b=o2a+32; \
  /* P1: A-k0 (8 rd), B-k0 n0/n1 (2 rd); stage B1(t+1) */ \
  _Pragma("unroll") \
  for (int mi=0;mi<8;++mi) aR[mi] = *(const bf16x8*)(aS0 + aRd + mi*1024); \
  bRa = *(const bf16x8*)(bS0 + bRd); \
  bRb = *(const bf16x8*)(bS0 + bRd + 1024); \
  GLOAD(bSrc0+o1, 65536 + (3-(DB))*16384); \
  GLOAD(bSrc1+o1, 65536 + (3-(DB))*16384 + 8192); \
  PHASE_MID; MFMA8x2(0,1); PHASE_END; \
  /* P2: B-k0 n2/n3; stage A0(t+2) */ \
  bRa = *(const bf16x8*)(bS0 + bRd + 2048); \
  bRb = *(const bf16x8*)(bS0 + bRd + 3072); \
  GLOAD(aSrc0+o2a, (DB)*16384); \
  GLOAD(aSrc1+o2a, (DB)*16384 + 8192); \
  PHASE_MID; MFMA8x2(2,3); PHASE_END; \
  /* P3: A-k1 (8 rd), B-k1 n0/n1; stage B0(t+2) */ \
  _Pragma("unroll") \
  for (int mi=0;mi<8;++mi) aR[mi] = *(const bf16x8*)(aS1 + aRd + mi*1024); \
  bRa = *(const bf16x8*)(bS1 + bRd); \
  bRb = *(const bf16x8*)(bS1 + bRd + 1024); \
  GLOAD(bSrc0+o2a, 65536 + (DB)*16384); \
  GLOAD(bSrc1+o2a, 65536 + (DB)*16384 + 8192); \
  PHASE_MID; MFMA8x2(0,1); PHASE_END; \
  /* P4: B-k1 n2/n3; stage A1(t+2); vmcnt(6) */ \
  bRa = *(const bf16x8*)(bS1 + bRd + 2048); \
  bRb = *(const bf16x8*)(bS1 + bRd + 3072); \
  GLOAD(aSrc0+o2b, ((DB)+1)*16384); \
  GLOAD(aSrc1+o2b, ((DB)+1)*16384 + 8192); \
  PHASE_MID; MFMA8x2(2,3); \
  __builtin_amdgcn_s_setprio(0); \
  asm volatile("s_waitcnt vmcnt(6)" ::: "memory"); \
  __builtin_amdgcn_s_barrier(); }while(0)

template<int WRITE_F32>
__global__ __launch_bounds__(512, 2) void k_gemm8p(const unsigned short* __restrict__ A,
                                                   const unsigned short* __restrict__ Bt,
                                                   void* __restrict__ Cout,
                                                   const float* __restrict__ bias,
                                                   int M, int N, int NTN, int NWG){
  __shared__ char smem[131072];   // A ring 4x16KB | B ring 4x16KB
  int wg = blockIdx.x;
  int cpx = NWG >> 3;
  int swz = (wg & 7)*cpx + (wg >> 3);          // bijective (NWG%8==0)
  int bm = swz / NTN, bn = swz - bm*NTN;
  int m0 = bm << 8, n0 = bn << 8;

  int tid = threadIdx.x;
  int w = tid >> 6, lane = tid & 63;
  int r = lane & 15, g4 = lane >> 4;
  int wr = w >> 2, wc = w & 3;

  // ds_read side: seg = g ^ (row&3) ^ ((row>>2)&3); per-thread constant
  int seg = g4 ^ (lane & 3) ^ ((lane >> 2) & 3);
  int aRd = (wr*128 + r)*64 + seg*16;          // byte offset within A slot
  int bRd = (wc*64  + r)*64 + seg*16;          // byte offset within B slot

  // staging side (pre-swizzled global source; linear LDS dest)
  int srow = tid >> 2;
  int gsw  = (tid & 3) ^ ((tid >> 2) & 3) ^ ((tid >> 4) & 3);
  const unsigned short* aSrc0 = A  + (size_t)(m0 + srow)*GK + gsw*8;
  const unsigned short* aSrc1 = aSrc0 + (size_t)128*GK;
  const unsigned short* bSrc0 = Bt + (size_t)(n0 + srow)*GK + gsw*8;
  const unsigned short* bSrc1 = bSrc0 + (size_t)128*GK;

  const f32x4 fz = {0.f,0.f,0.f,0.f};
  f32x4 acc[8][4];
  #pragma unroll
  for (int mi=0;mi<8;++mi)
    #pragma unroll
    for (int ni=0;ni<4;++ni) acc[mi][ni] = fz;
  bf16x8 aR[8], bRa, bRb;

  // ---- prologue: 7 half-tiles (A0,B0,A1,B1 of tile0; A0,B0,A1 of tile1) ----
  GLOAD(aSrc0+ 0,     0); GLOAD(aSrc1+ 0,  8192);
  GLOAD(bSrc0+ 0, 65536); GLOAD(bSrc1+ 0, 65536+ 8192);
  GLOAD(aSrc0+32, 16384); GLOAD(aSrc1+32, 16384+8192);
  GLOAD(bSrc0+32, 65536+16384); GLOAD(bSrc1+32, 65536+16384+8192);
  GLOAD(aSrc0+64, 32768); GLOAD(aSrc1+64, 32768+8192);
  GLOAD(bSrc0+64, 65536+32768); GLOAD(bSrc1+64, 65536+32768+8192);
  GLOAD(aSrc0+96, 49152); GLOAD(aSrc1+96, 49152+8192);
  asm volatile("s_waitcnt vmcnt(6)" ::: "memory");
  __builtin_amdgcn_s_barrier();

  #pragma unroll 1
  for (int tt=0; tt<NTK; tt+=2){
    TILE_BODY(tt,   0);
    TILE_BODY(tt+1, 2);
  }
  asm volatile("s_waitcnt vmcnt(0)" ::: "memory");

  // ---- epilogue: C/D layout col=lane&15, row=(lane>>4)*4+q ----
  #pragma unroll
  for (int mi=0;mi<8;++mi){
    #pragma unroll
    for (int ni=0;ni<4;++ni){
      int col = n0 + wc*64 + ni*16 + r;
      float bb = WRITE_F32 ? (bias ? bias[col] : 0.f) : 0.f;
      #pragma unroll
      for (int q=0;q<4;++q){
        int row = m0 + wr*128 + mi*16 + g4*4 + q;
        float val = acc[mi][ni][q];
        if (WRITE_F32) ((float*)Cout)[(size_t)row*N + col] = val + bb;
        else ((unsigned short*)Cout)[(size_t)row*N + col] = f2b(val);
      }
    }
  }
}

// ---------------- dRoFE + attention (unchanged) ----------------
__global__ __launch_bounds__(256) void k_attn(const unsigned short* __restrict__ qkv,
                                              const float* __restrict__ demo,
                                              const float* __restrict__ cs,
                                              const float* __restrict__ sn,
                                              unsigned short* __restrict__ out){
  __shared__ float s_cs[SEQ*DH], s_sn[SEQ*DH];
  int tid = threadIdx.x;
  for (int t=tid; t<SEQ*DH; t+=256){ s_cs[t]=cs[t]; s_sn[t]=sn[t]; }
  __syncthreads();

  int pr = tid / 9, i = tid - pr*9;
  int pair = blockIdx.x*PPB + pr;
  if (pr >= PPB || pair >= NPAIR) return;
  int b = pair / HEADS, h = pair - b*HEADS;
  float age = demo[2*b], gen = demo[2*b+1];
  const unsigned short* base = qkv + (size_t)b*SEQ*NQKV + h*DH;

  float qr[64];
  {
    const u16x8* qp = (const u16x8*)(base + (size_t)i*NQKV);
    #pragma unroll
    for (int t8=0;t8<8;++t8){
      u16x8 v = qp[t8];
      #pragma unroll
      for (int e=0;e<8;e+=2){
        int d = t8*8+e;
        float x0=b2f(v[e]), x1=b2f(v[e+1]);
        qr[d]   = age*x0*s_cs[i*64+d]   - gen*x1*s_sn[i*64+d];
        qr[d+1] = age*x1*s_cs[i*64+d+1] + gen*x0*s_sn[i*64+d+1];
      }
    }
  }

  float s[9]; float mx = -1e30f;
  #pragma unroll
  for (int j=0;j<9;++j){
    const u16x8* kp = (const u16x8*)(base + (size_t)j*NQKV + CDIM);
    float acc = 0.f;
    #pragma unroll
    for (int t8=0;t8<8;++t8){
      u16x8 v = kp[t8];
      #pragma unroll
      for (int e=0;e<8;e+=2){
        int d = t8*8+e;
        float x0=b2f(v[e]), x1=b2f(v[e+1]);
        float k0 = age*x0*s_cs[j*64+d]   - gen*x1*s_sn[j*64+d];
        float k1 = age*x1*s_cs[j*64+d+1] + gen*x0*s_sn[j*64+d+1];
        acc += qr[d]*k0 + qr[d+1]*k1;
      }
    }
    s[j] = acc * 0.125f;
    mx = fmaxf(mx, s[j]);
  }
  float den = 0.f;
  #pragma unroll
  for (int j=0;j<9;++j){ s[j] = __expf(s[j]-mx); den += s[j]; }
  float inv = 1.f/den;

  float o[64];
  #pragma unroll
  for (int d=0;d<64;++d) o[d]=0.f;
  #pragma unroll
  for (int j=0;j<9;++j){
    float p = s[j]*inv;
    const u16x8* vp = (const u16x8*)(base + (size_t)j*NQKV + 2*CDIM);
    #pragma unroll
    for (int t8=0;t8<8;++t8){
      u16x8 v = vp[t8];
      #pragma unroll
      for (int e=0;e<8;++e) o[t8*8+e] += p*b2f(v[e]);
    }
  }

  u16x8* op = (u16x8*)(out + (size_t)(b*SEQ+i)*CDIM + h*DH);
  #pragma unroll
  for (int t8=0;t8<8;++t8){
    u16x8 v;
    #pragma unroll
    for (int e=0;e<8;++e) v[e]=f2b(o[t8*8+e]);
    op[t8]=v;
  }
}

extern "C" void kernel_launch(void* const* d_in, const int* in_sizes, int n_in,
                              void* d_out, int out_size, void* d_ws, size_t ws_size,
                              hipStream_t stream){
  const float* x    = (const float*)d_in[0];
  const float* demo = (const float*)d_in[1];
  const float* Wq   = (const float*)d_in[2];
  const float* Wp   = (const float*)d_in[3];
  const float* bp   = (const float*)d_in[4];
  float* outp = (float*)d_out;

  char* wsb = (char*)d_ws;
  unsigned short* xb   = (unsigned short*)wsb;              // x bf16; reused as attn out
  unsigned short* Wq_t = (unsigned short*)(wsb + 56623104); // [2304][768]
  unsigned short* Wp_t = (unsigned short*)(wsb + 60162048); // [768][768]
  float* cs = (float*)(wsb + 61341696);
  float* sn = cs + SEQ*DH;
  unsigned short* qkv  = (unsigned short*)(wsb + 61346304); // [36864][2304] bf16

  k_conv <<< MROWS*CDIM/1024, 256, 0, stream >>> (x, xb);
  k_tconv<<< CDIM*NQKV/256,  256, 0, stream >>> (Wq, Wq_t, CDIM, NQKV);
  k_tconv<<< CDIM*CDIM/256,  256, 0, stream >>> (Wp, Wp_t, CDIM, CDIM);
  k_table<<< 1, 576, 0, stream >>> (cs, sn);

  {
    int nwg = (MROWS/256)*(NQKV/256);   // 144*9 = 1296, %8==0
    k_gemm8p<0><<< nwg, 512, 0, stream >>>
        (xb, Wq_t, qkv, nullptr, MROWS, NQKV, NQKV/256, nwg);
  }

  k_attn <<< (NPAIR + PPB - 1)/PPB, 256, 0, stream >>> (qkv, demo, cs, sn, xb);

  {
    int nwg = (MROWS/256)*(CDIM/256);   // 144*3 = 432, %8==0
    k_gemm8p<1><<< nwg, 512, 0, stream >>>
        (xb, Wp_t, outp, bp, MROWS, CDIM, CDIM/256, nwg);
  }
}

// Round 3
// 364.404 us; speedup vs baseline: 1.2167x; 1.0907x over previous
//
#include <hip/hip_runtime.h>
#include <cstdint>
#include <cstddef>

typedef __bf16  bf16x8 __attribute__((ext_vector_type(8)));
typedef float   f32x4  __attribute__((ext_vector_type(4)));
typedef unsigned short u16x8 __attribute__((ext_vector_type(8)));
typedef unsigned short u16x4 __attribute__((ext_vector_type(4)));

#define B_SZ  4096
#define SEQ   9
#define CDIM  768
#define HEADS 12
#define DH    64
#define MROWS (B_SZ*SEQ)      // 36864
#define NQKV  (3*CDIM)        // 2304
#define NPAIR (B_SZ*HEADS)    // 49152
#define PPB   28
#define GK    768             // K for both GEMMs
#define NTK   12              // K-tiles (GK/64)

#define AS1 __attribute__((address_space(1)))
#define AS3 __attribute__((address_space(3)))

__device__ inline float b2f(unsigned short u){
  union{unsigned i; float f;} x; x.i = ((unsigned)u)<<16; return x.f;
}
__device__ inline unsigned short f2b(float f){ // RNE fp32->bf16
  unsigned x = __float_as_uint(f);
  return (unsigned short)((x + 0x7fffu + ((x>>16)&1u)) >> 16);
}

// ---------------- K0a: fp32 -> bf16, vectorized ----------------
__global__ __launch_bounds__(256) void k_conv(const float* __restrict__ in,
                                              unsigned short* __restrict__ out){
  int t = blockIdx.x*256 + threadIdx.x;
  float4 v = ((const float4*)in)[t];
  u16x4 o; o.x=f2b(v.x); o.y=f2b(v.y); o.z=f2b(v.z); o.w=f2b(v.w);
  ((u16x4*)out)[t] = o;
}

// ------- K0b: transpose+convert: in fp32 [R][C] -> out bf16 [C][R] -------
__global__ __launch_bounds__(256) void k_tconv(const float* __restrict__ in,
                                               unsigned short* __restrict__ out,
                                               int R, int C){
  int t = blockIdx.x*256 + threadIdx.x;
  int c = t / R, r = t - c*R;
  out[t] = f2b(in[(size_t)r*C + c]);
}

// ---------------- K0c: dRoFE cos/sin table [9][64] ----------------
__global__ void k_table(float* __restrict__ cs, float* __restrict__ sn){
  int t = threadIdx.x;
  if (t >= SEQ*DH) return;
  const float blo[9] = {1.f,4.f,8.f,10.f,12.f,30.f,1.f,8.f,1.f};
  const float bhi[9] = {4.f,8.f,10.f,12.f,30.f,45.f,8.f,30.f,45.f};
  int n = t / DH, d = t - n*DH;
  int f = (d < 32) ? (d>>1) : ((d-32)>>1);
  float freq = 3.14159265358979f * (1.0f + (4.0f/15.0f)*(float)f);
  float band = (d < 32) ? blo[n] : bhi[n];
  float ang = band * freq;
  cs[t] = cosf(ang);
  sn[t] = sinf(ang);
}

// ================= 256x256 8-phase GEMM (T2+T3+T4+T5) =================
// C[M][N] = A[M][GK] * Bt[N][GK]^T.  512 thr (8 waves 2Mx4N), BK=64 staged
// as two K-halves; per-matrix 4-slot ring (2dbuf x 2half), 128 KiB LDS.
// LDS swizzle = m201 st_16x32 on 64B rows: byte-bit5 ^= row-bit3.
#define GLOAD(SRC, LDSOFF) \
  __builtin_amdgcn_global_load_lds((const AS1 void*)(SRC), \
      (AS3 void*)(smem + (LDSOFF) + (w<<10)), 16, 0, 0)

#define PHASE_MID  do{ __builtin_amdgcn_s_barrier(); \
  asm volatile("s_waitcnt lgkmcnt(0)" ::: "memory"); \
  __builtin_amdgcn_sched_barrier(0); \
  __builtin_amdgcn_s_setprio(1); }while(0)
#define PHASE_END  do{ __builtin_amdgcn_s_setprio(0); \
  __builtin_amdgcn_s_barrier(); }while(0)

#define MFMA8x2(NA, NB) do{ \
  _Pragma("unroll") \
  for (int mi=0;mi<8;++mi){ \
    acc[mi][NA] = __builtin_amdgcn_mfma_f32_16x16x32_bf16(aR[mi], bRa, acc[mi][NA], 0,0,0); \
    acc[mi][NB] = __builtin_amdgcn_mfma_f32_16x16x32_bf16(aR[mi], bRb, acc[mi][NB], 0,0,0); } }while(0)

// One K-tile = 4 phases. DB is compile-time (0 or 2).
#define TILE_BODY(T, DB) do{ \
  const char* aS0 = smem + (DB)*16384; \
  const char* aS1 = smem + ((DB)+1)*16384; \
  const char* bS0 = smem + 65536 + (DB)*16384; \
  const char* bS1 = smem + 65536 + ((DB)+1)*16384; \
  int u1=(T)+1; if(u1>NTK-1)u1=NTK-1; int u2=(T)+2; if(u2>NTK-1)u2=NTK-1; \
  size_t o1=(size_t)u1*64+32, o2a=(size_t)u2*64, o2b=o2a+32; \
  /* P1: A-k0 (8 rd), B-k0 n0/n1 (2 rd); stage B1(t+1) */ \
  _Pragma("unroll") \
  for (int mi=0;mi<8;++mi) aR[mi] = *(const bf16x8*)(aS0 + aRd + mi*1024); \
  bRa = *(const bf16x8*)(bS0 + bRd); \
  bRb = *(const bf16x8*)(bS0 + bRd + 1024); \
  GLOAD(bSrc0+o1, 65536 + (3-(DB))*16384); \
  GLOAD(bSrc1+o1, 65536 + (3-(DB))*16384 + 8192); \
  PHASE_MID; MFMA8x2(0,1); PHASE_END; \
  /* P2: B-k0 n2/n3; stage A0(t+2) */ \
  bRa = *(const bf16x8*)(bS0 + bRd + 2048); \
  bRb = *(const bf16x8*)(bS0 + bRd + 3072); \
  GLOAD(aSrc0+o2a, (DB)*16384); \
  GLOAD(aSrc1+o2a, (DB)*16384 + 8192); \
  PHASE_MID; MFMA8x2(2,3); PHASE_END; \
  /* P3: A-k1 (8 rd), B-k1 n0/n1; stage B0(t+2) */ \
  _Pragma("unroll") \
  for (int mi=0;mi<8;++mi) aR[mi] = *(const bf16x8*)(aS1 + aRd + mi*1024); \
  bRa = *(const bf16x8*)(bS1 + bRd); \
  bRb = *(const bf16x8*)(bS1 + bRd + 1024); \
  GLOAD(bSrc0+o2a, 65536 + (DB)*16384); \
  GLOAD(bSrc1+o2a, 65536 + (DB)*16384 + 8192); \
  PHASE_MID; MFMA8x2(0,1); PHASE_END; \
  /* P4: B-k1 n2/n3; stage A1(t+2); vmcnt(6) */ \
  bRa = *(const bf16x8*)(bS1 + bRd + 2048); \
  bRb = *(const bf16x8*)(bS1 + bRd + 3072); \
  GLOAD(aSrc0+o2b, ((DB)+1)*16384); \
  GLOAD(aSrc1+o2b, ((DB)+1)*16384 + 8192); \
  PHASE_MID; MFMA8x2(2,3); \
  __builtin_amdgcn_s_setprio(0); \
  asm volatile("s_waitcnt vmcnt(6)" ::: "memory"); \
  __builtin_amdgcn_s_barrier(); }while(0)

template<int WRITE_F32>
__global__ __launch_bounds__(512, 2) void k_gemm8p(const unsigned short* __restrict__ A,
                                                   const unsigned short* __restrict__ Bt,
                                                   void* __restrict__ Cout,
                                                   const float* __restrict__ bias,
                                                   int M, int N, int NTN, int NWG){
  __shared__ char smem[131072];   // A ring 4x16KB | B ring 4x16KB
  int wg = blockIdx.x;
  int cpx = NWG >> 3;
  int swz = (wg & 7)*cpx + (wg >> 3);          // bijective (NWG%8==0)
  int bm = swz / NTN, bn = swz - bm*NTN;
  int m0 = bm << 8, n0 = bn << 8;

  int tid = threadIdx.x;
  int w = tid >> 6, lane = tid & 63;
  int r = lane & 15, g4 = lane >> 4;
  int wr = w >> 2, wc = w & 3;

  // m201 st_16x32 read-side: 16B-granule g4 ^= 2*row_bit3 (row bit3 = r>>3)
  int seg = g4 ^ (((r >> 3) & 1) << 1);
  int aRd = (wr*128 + r)*64 + seg*16;          // byte offset within A slot
  int bRd = (wc*64  + r)*64 + seg*16;          // byte offset within B slot

  // staging side (pre-swizzled global source; linear LDS dest).
  // LDS row written by this thread = tid>>2; its bit3 = (tid>>5)&1.
  int srow = tid >> 2;
  int gsw  = (tid & 3) ^ (((tid >> 5) & 1) << 1);
  const unsigned short* aSrc0 = A  + (size_t)(m0 + srow)*GK + gsw*8;
  const unsigned short* aSrc1 = aSrc0 + (size_t)128*GK;
  const unsigned short* bSrc0 = Bt + (size_t)(n0 + srow)*GK + gsw*8;
  const unsigned short* bSrc1 = bSrc0 + (size_t)128*GK;

  const f32x4 fz = {0.f,0.f,0.f,0.f};
  f32x4 acc[8][4];
  #pragma unroll
  for (int mi=0;mi<8;++mi)
    #pragma unroll
    for (int ni=0;ni<4;++ni) acc[mi][ni] = fz;
  bf16x8 aR[8], bRa, bRb;

  // ---- prologue: 7 half-tiles ----
  GLOAD(aSrc0+ 0,     0); GLOAD(aSrc1+ 0,  8192);
  GLOAD(bSrc0+ 0, 65536); GLOAD(bSrc1+ 0, 65536+ 8192);
  GLOAD(aSrc0+32, 16384); GLOAD(aSrc1+32, 16384+8192);
  GLOAD(bSrc0+32, 65536+16384); GLOAD(bSrc1+32, 65536+16384+8192);
  GLOAD(aSrc0+64, 32768); GLOAD(aSrc1+64, 32768+8192);
  GLOAD(bSrc0+64, 65536+32768); GLOAD(bSrc1+64, 65536+32768+8192);
  GLOAD(aSrc0+96, 49152); GLOAD(aSrc1+96, 49152+8192);
  asm volatile("s_waitcnt vmcnt(6)" ::: "memory");
  __builtin_amdgcn_s_barrier();

  #pragma unroll 1
  for (int tt=0; tt<NTK; tt+=2){
    TILE_BODY(tt,   0);
    TILE_BODY(tt+1, 2);
  }
  asm volatile("s_waitcnt vmcnt(0)" ::: "memory");

  // ---- epilogue: C/D layout col=lane&15, row=(lane>>4)*4+q ----
  if (WRITE_F32){
    #pragma unroll
    for (int mi=0;mi<8;++mi){
      #pragma unroll
      for (int ni=0;ni<4;++ni){
        int col = n0 + wc*64 + ni*16 + r;
        float bb = bias ? bias[col] : 0.f;
        #pragma unroll
        for (int q=0;q<4;++q){
          int row = m0 + wr*128 + mi*16 + g4*4 + q;
          ((float*)Cout)[(size_t)row*N + col] = acc[mi][ni][q] + bb;
        }
      }
    }
  } else {
    // head-major qkv: idx = ((b*12+h)*9+i)*192 + which*64 + d
    #pragma unroll
    for (int mi=0;mi<8;++mi){
      #pragma unroll
      for (int q=0;q<4;++q){
        int row = m0 + wr*128 + mi*16 + g4*4 + q;
        int bb = row / 9;                 // magic-mul
        int ii = row - bb*9;
        size_t rb = (size_t)bb*HEADS;
        #pragma unroll
        for (int ni=0;ni<4;++ni){
          int col = n0 + wc*64 + ni*16 + r;
          int which = (col >= 1536) ? 2 : (col >= 768 ? 1 : 0);
          int rem = col - which*768;
          int h = rem >> 6, d = rem & 63;
          size_t idx = ((rb + h)*9 + ii)*192 + which*64 + d;
          ((unsigned short*)Cout)[idx] = f2b(acc[mi][ni][q]);
        }
      }
    }
  }
}

// ---------------- dRoFE + attention, head-major qkv ----------------
// qkv[pair][row][ q(0..63) | k(64..127) | v(128..191) ], pair = b*12+h.
// Cooperative K-rope: thread (pr,i) ropes K-row i into LDS (f32, padded).
__global__ __launch_bounds__(256) void k_attn(const unsigned short* __restrict__ qkv,
                                              const float* __restrict__ demo,
                                              const float* __restrict__ cs,
                                              const float* __restrict__ sn,
                                              unsigned short* __restrict__ out){
  __shared__ float kl[PPB][SEQ][68];     // 28*9*68*4 = 68544 B (padded rows)
  __shared__ float s_cs[SEQ*DH], s_sn[SEQ*DH];
  int tid = threadIdx.x;
  for (int t=tid; t<SEQ*DH; t+=256){ s_cs[t]=cs[t]; s_sn[t]=sn[t]; }

  int pr = tid / 9, i = tid - pr*9;
  int pair = blockIdx.x*PPB + pr;
  bool act = (pr < PPB) && (pair < NPAIR);
  int b = 0, h = 0; float age = 0.f, gen = 0.f;
  const unsigned short* base = qkv;
  if (act){
    b = pair / HEADS; h = pair - b*HEADS;
    age = demo[2*b]; gen = demo[2*b+1];
    base = qkv + (size_t)pair*(SEQ*192);
  }
  __syncthreads();   // cs/sn staged

  float qr[64];
  if (act){
    const u16x8* qp = (const u16x8*)(base + (size_t)i*192);
    const u16x8* kp = (const u16x8*)(base + (size_t)i*192 + 64);
    #pragma unroll
    for (int t8=0;t8<8;++t8){
      u16x8 qv = qp[t8], kv = kp[t8];
      #pragma unroll
      for (int e=0;e<8;e+=2){
        int d = t8*8+e;
        float c0=s_cs[i*64+d], s0=s_sn[i*64+d];
        float c1=s_cs[i*64+d+1], s1=s_sn[i*64+d+1];
        float q0=b2f(qv[e]), q1=b2f(qv[e+1]);
        qr[d]   = age*q0*c0 - gen*q1*s0;
        qr[d+1] = age*q1*c1 + gen*q0*s1;
        float k0=b2f(kv[e]), k1=b2f(kv[e+1]);
        kl[pr][i][d]   = age*k0*c0 - gen*k1*s0;
        kl[pr][i][d+1] = age*k1*c1 + gen*k0*s1;
      }
    }
  }
  __syncthreads();   // roped K ready

  if (!act) return;

  float s[9]; float mx = -1e30f;
  #pragma unroll
  for (int j=0;j<9;++j){
    const float4* kr = (const float4*)(&kl[pr][j][0]);
    float acc = 0.f;
    #pragma unroll
    for (int d4=0;d4<16;++d4){
      float4 kv = kr[d4];
      acc += qr[d4*4]*kv.x + qr[d4*4+1]*kv.y + qr[d4*4+2]*kv.z + qr[d4*4+3]*kv.w;
    }
    s[j] = acc * 0.125f;
    mx = fmaxf(mx, s[j]);
  }
  float den = 0.f;
  #pragma unroll
  for (int j=0;j<9;++j){ s[j] = __expf(s[j]-mx); den += s[j]; }
  float inv = 1.f/den;

  float o[64];
  #pragma unroll
  for (int d=0;d<64;++d) o[d]=0.f;
  #pragma unroll
  for (int j=0;j<9;++j){
    float p = s[j]*inv;
    const u16x8* vp = (const u16x8*)(base + (size_t)j*192 + 128);
    #pragma unroll
    for (int t8=0;t8<8;++t8){
      u16x8 v = vp[t8];
      #pragma unroll
      for (int e=0;e<8;++e) o[t8*8+e] += p*b2f(v[e]);
    }
  }

  u16x8* op = (u16x8*)(out + (size_t)(b*SEQ+i)*CDIM + h*DH);
  #pragma unroll
  for (int t8=0;t8<8;++t8){
    u16x8 v;
    #pragma unroll
    for (int e=0;e<8;++e) v[e]=f2b(o[t8*8+e]);
    op[t8]=v;
  }
}

extern "C" void kernel_launch(void* const* d_in, const int* in_sizes, int n_in,
                              void* d_out, int out_size, void* d_ws, size_t ws_size,
                              hipStream_t stream){
  const float* x    = (const float*)d_in[0];
  const float* demo = (const float*)d_in[1];
  const float* Wq   = (const float*)d_in[2];
  const float* Wp   = (const float*)d_in[3];
  const float* bp   = (const float*)d_in[4];
  float* outp = (float*)d_out;

  char* wsb = (char*)d_ws;
  unsigned short* xb   = (unsigned short*)wsb;              // x bf16; reused as attn out
  unsigned short* Wq_t = (unsigned short*)(wsb + 56623104); // [2304][768]
  unsigned short* Wp_t = (unsigned short*)(wsb + 60162048); // [768][768]
  float* cs = (float*)(wsb + 61341696);
  float* sn = cs + SEQ*DH;
  unsigned short* qkv  = (unsigned short*)(wsb + 61346304); // head-major [49152][9][192]

  k_conv <<< MROWS*CDIM/1024, 256, 0, stream >>> (x, xb);
  k_tconv<<< CDIM*NQKV/256,  256, 0, stream >>> (Wq, Wq_t, CDIM, NQKV);
  k_tconv<<< CDIM*CDIM/256,  256, 0, stream >>> (Wp, Wp_t, CDIM, CDIM);
  k_table<<< 1, 576, 0, stream >>> (cs, sn);

  {
    int nwg = (MROWS/256)*(NQKV/256);   // 144*9 = 1296, %8==0
    k_gemm8p<0><<< nwg, 512, 0, stream >>>
        (xb, Wq_t, qkv, nullptr, MROWS, NQKV, NQKV/256, nwg);
  }

  k_attn <<< (NPAIR + PPB - 1)/PPB, 256, 0, stream >>> (qkv, demo, cs, sn, xb);

  {
    int nwg = (MROWS/256)*(CDIM/256);   // 144*3 = 432, %8==0
    k_gemm8p<1><<< nwg, 512, 0, stream >>>
        (xb, Wp_t, outp, bp, MROWS, CDIM, CDIM/256, nwg);
  }
}

// Round 4
// 361.901 us; speedup vs baseline: 1.2251x; 1.0069x over previous
//
#include <hip/hip_runtime.h>
#include <cstdint>
#include <cstddef>

typedef __bf16  bf16x8 __attribute__((ext_vector_type(8)));
typedef float   f32x4  __attribute__((ext_vector_type(4)));
typedef unsigned short u16x8 __attribute__((ext_vector_type(8)));
typedef unsigned short u16x4 __attribute__((ext_vector_type(4)));

#define B_SZ  4096
#define SEQ   9
#define CDIM  768
#define HEADS 12
#define DH    64
#define MROWS (B_SZ*SEQ)      // 36864
#define NQKV  (3*CDIM)        // 2304
#define NPAIR (B_SZ*HEADS)    // 49152
#define PPB   28
#define GK    768             // K for both GEMMs
#define NTK   12              // K-tiles for 256^2 kernel (GK/64)
#define NT2   24              // K-tiles for 256x128 kernel (GK/32)

#define AS1 __attribute__((address_space(1)))
#define AS3 __attribute__((address_space(3)))

__device__ inline float b2f(unsigned short u){
  union{unsigned i; float f;} x; x.i = ((unsigned)u)<<16; return x.f;
}
__device__ inline unsigned short f2b(float f){ // RNE fp32->bf16
  unsigned x = __float_as_uint(f);
  return (unsigned short)((x + 0x7fffu + ((x>>16)&1u)) >> 16);
}

// ---------------- K0a: fp32 -> bf16, vectorized ----------------
__global__ __launch_bounds__(256) void k_conv(const float* __restrict__ in,
                                              unsigned short* __restrict__ out){
  int t = blockIdx.x*256 + threadIdx.x;
  float4 v = ((const float4*)in)[t];
  u16x4 o; o.x=f2b(v.x); o.y=f2b(v.y); o.z=f2b(v.z); o.w=f2b(v.w);
  ((u16x4*)out)[t] = o;
}

// ------- K0b: transpose+convert: in fp32 [R][C] -> out bf16 [C][R] -------
__global__ __launch_bounds__(256) void k_tconv(const float* __restrict__ in,
                                               unsigned short* __restrict__ out,
                                               int R, int C){
  int t = blockIdx.x*256 + threadIdx.x;
  int c = t / R, r = t - c*R;
  out[t] = f2b(in[(size_t)r*C + c]);
}

// ---------------- K0c: dRoFE cos/sin table [9][64] ----------------
__global__ void k_table(float* __restrict__ cs, float* __restrict__ sn){
  int t = threadIdx.x;
  if (t >= SEQ*DH) return;
  const float blo[9] = {1.f,4.f,8.f,10.f,12.f,30.f,1.f,8.f,1.f};
  const float bhi[9] = {4.f,8.f,10.f,12.f,30.f,45.f,8.f,30.f,45.f};
  int n = t / DH, d = t - n*DH;
  int f = (d < 32) ? (d>>1) : ((d-32)>>1);
  float freq = 3.14159265358979f * (1.0f + (4.0f/15.0f)*(float)f);
  float band = (d < 32) ? blo[n] : bhi[n];
  float ang = band * freq;
  cs[t] = cosf(ang);
  sn[t] = sinf(ang);
}

// ---- shared GEMM phase machinery ----
#define GLOAD(SRC, LDSOFF) \
  __builtin_amdgcn_global_load_lds((const AS1 void*)(SRC), \
      (AS3 void*)(smem + (LDSOFF) + (w<<10)), 16, 0, 0)

#define PHASE_MID  do{ __builtin_amdgcn_s_barrier(); \
  asm volatile("s_waitcnt lgkmcnt(0)" ::: "memory"); \
  __builtin_amdgcn_sched_barrier(0); \
  __builtin_amdgcn_s_setprio(1); }while(0)
#define PHASE_END  do{ __builtin_amdgcn_s_setprio(0); \
  __builtin_amdgcn_s_barrier(); }while(0)

// ================= GEMM1: 256x256, BK=64, 8-phase, balanced quadrants =====
// 512 thr (8 waves 2Mx4N); per phase: {4xA(+4xB)} reads + 16 MFMA (mi-half).
#define RD_A(SLOT, H) do{ _Pragma("unroll") \
  for (int m=0;m<4;++m) aQ[m] = *(const bf16x8*)((SLOT) + aRd + ((H)*4+m)*1024); }while(0)
#define RD_B(SLOT) do{ _Pragma("unroll") \
  for (int n=0;n<4;++n) bR[n] = *(const bf16x8*)((SLOT) + bRd + n*1024); }while(0)
#define MFMA_Q(H) do{ _Pragma("unroll") \
  for (int m=0;m<4;++m){ _Pragma("unroll") \
    for (int n=0;n<4;++n) \
      acc[(H)*4+m][n] = __builtin_amdgcn_mfma_f32_16x16x32_bf16(aQ[m], bR[n], acc[(H)*4+m][n], 0,0,0); } }while(0)

#define TILE_BODY(T, DB) do{ \
  const char* aS0 = smem + (DB)*16384; \
  const char* aS1 = smem + ((DB)+1)*16384; \
  const char* bS0 = smem + 65536 + (DB)*16384; \
  const char* bS1 = smem + 65536 + ((DB)+1)*16384; \
  int u1=(T)+1; if(u1>NTK-1)u1=NTK-1; int u2=(T)+2; if(u2>NTK-1)u2=NTK-1; \
  size_t o1=(size_t)u1*64+32, o2a=(size_t)u2*64, o2b=o2a+32; \
  /* P1: A mi0-3 k0, B k0; stage B1(t+1) */ \
  RD_A(aS0,0); RD_B(bS0); \
  GLOAD(bSrc0+o1, 65536 + (3-(DB))*16384); \
  GLOAD(bSrc1+o1, 65536 + (3-(DB))*16384 + 8192); \
  PHASE_MID; MFMA_Q(0); PHASE_END; \
  /* P2: A mi4-7 k0; stage A0(t+2) */ \
  RD_A(aS0,1); \
  GLOAD(aSrc0+o2a, (DB)*16384); \
  GLOAD(aSrc1+o2a, (DB)*16384 + 8192); \
  PHASE_MID; MFMA_Q(1); PHASE_END; \
  /* P3: A mi0-3 k1, B k1; stage B0(t+2) */ \
  RD_A(aS1,0); RD_B(bS1); \
  GLOAD(bSrc0+o2a, 65536 + (DB)*16384); \
  GLOAD(bSrc1+o2a, 65536 + (DB)*16384 + 8192); \
  PHASE_MID; MFMA_Q(0); PHASE_END; \
  /* P4: A mi4-7 k1; stage A1(t+2); vmcnt(6) */ \
  RD_A(aS1,1); \
  GLOAD(aSrc0+o2b, ((DB)+1)*16384); \
  GLOAD(aSrc1+o2b, ((DB)+1)*16384 + 8192); \
  PHASE_MID; MFMA_Q(1); \
  __builtin_amdgcn_s_setprio(0); \
  asm volatile("s_waitcnt vmcnt(6)" ::: "memory"); \
  __builtin_amdgcn_s_barrier(); }while(0)

template<int WRITE_F32>
__global__ __launch_bounds__(512, 2) void k_gemm8p(const unsigned short* __restrict__ A,
                                                   const unsigned short* __restrict__ Bt,
                                                   void* __restrict__ Cout,
                                                   const float* __restrict__ bias,
                                                   int M, int N, int NTN, int NWG){
  __shared__ char smem[131072];   // A ring 4x16KB | B ring 4x16KB
  int wg = blockIdx.x;
  int cpx = NWG >> 3;
  int swz = (wg & 7)*cpx + (wg >> 3);          // bijective (NWG%8==0)
  int bm = swz / NTN, bn = swz - bm*NTN;
  int m0 = bm << 8, n0 = bn << 8;

  int tid = threadIdx.x;
  int w = tid >> 6, lane = tid & 63;
  int r = lane & 15, g4 = lane >> 4;
  int wr = w >> 2, wc = w & 3;

  // st_16x32 read-side: 16B-granule g4 ^= 2*row_bit3
  int seg = g4 ^ (((r >> 3) & 1) << 1);
  int aRd = (wr*128 + r)*64 + seg*16;
  int bRd = (wc*64  + r)*64 + seg*16;

  // staging side (pre-swizzled global source; linear LDS dest)
  int srow = tid >> 2;
  int gsw  = (tid & 3) ^ (((tid >> 5) & 1) << 1);
  const unsigned short* aSrc0 = A  + (size_t)(m0 + srow)*GK + gsw*8;
  const unsigned short* aSrc1 = aSrc0 + (size_t)128*GK;
  const unsigned short* bSrc0 = Bt + (size_t)(n0 + srow)*GK + gsw*8;
  const unsigned short* bSrc1 = bSrc0 + (size_t)128*GK;

  const f32x4 fz = {0.f,0.f,0.f,0.f};
  f32x4 acc[8][4];
  #pragma unroll
  for (int mi=0;mi<8;++mi)
    #pragma unroll
    for (int ni=0;ni<4;++ni) acc[mi][ni] = fz;
  bf16x8 aQ[4], bR[4];

  // ---- prologue: 7 half-tiles ----
  GLOAD(aSrc0+ 0,     0); GLOAD(aSrc1+ 0,  8192);
  GLOAD(bSrc0+ 0, 65536); GLOAD(bSrc1+ 0, 65536+ 8192);
  GLOAD(aSrc0+32, 16384); GLOAD(aSrc1+32, 16384+8192);
  GLOAD(bSrc0+32, 65536+16384); GLOAD(bSrc1+32, 65536+16384+8192);
  GLOAD(aSrc0+64, 32768); GLOAD(aSrc1+64, 32768+8192);
  GLOAD(bSrc0+64, 65536+32768); GLOAD(bSrc1+64, 65536+32768+8192);
  GLOAD(aSrc0+96, 49152); GLOAD(aSrc1+96, 49152+8192);
  asm volatile("s_waitcnt vmcnt(6)" ::: "memory");
  __builtin_amdgcn_s_barrier();

  #pragma unroll 1
  for (int tt=0; tt<NTK; tt+=2){
    TILE_BODY(tt,   0);
    TILE_BODY(tt+1, 2);
  }
  asm volatile("s_waitcnt vmcnt(0)" ::: "memory");

  // ---- epilogue: C/D layout col=lane&15, row=(lane>>4)*4+q ----
  if (WRITE_F32){
    #pragma unroll
    for (int mi=0;mi<8;++mi){
      #pragma unroll
      for (int ni=0;ni<4;++ni){
        int col = n0 + wc*64 + ni*16 + r;
        float bb = bias ? bias[col] : 0.f;
        #pragma unroll
        for (int q=0;q<4;++q){
          int row = m0 + wr*128 + mi*16 + g4*4 + q;
          ((float*)Cout)[(size_t)row*N + col] = acc[mi][ni][q] + bb;
        }
      }
    }
  } else {
    // head-major qkv: idx = ((b*12+h)*9+i)*192 + which*64 + d
    #pragma unroll
    for (int mi=0;mi<8;++mi){
      #pragma unroll
      for (int q=0;q<4;++q){
        int row = m0 + wr*128 + mi*16 + g4*4 + q;
        int bb = row / 9;
        int ii = row - bb*9;
        size_t rb = (size_t)bb*HEADS;
        #pragma unroll
        for (int ni=0;ni<4;++ni){
          int col = n0 + wc*64 + ni*16 + r;
          int which = (col >= 1536) ? 2 : (col >= 768 ? 1 : 0);
          int rem = col - which*768;
          int h = rem >> 6, d = rem & 63;
          size_t idx = ((rb + h)*9 + ii)*192 + which*64 + d;
          ((unsigned short*)Cout)[idx] = f2b(acc[mi][ni][q]);
        }
      }
    }
  }
}

// ============ GEMM2: 256x128, BK=32, 3-slot ring, 2 blocks/CU ============
// 512 thr (8 waves 4Mx2N), wave out 64x64, acc 16 frags (64 VGPR).
// LDS 72KB: A slots 3x16KB @0, B slots 3x8KB @49152. Prefetch distance 2.
#define TILE2(T, SL, SP) do{ \
  const char* aS = smem + (SL)*16384; \
  const char* bS = smem + 49152 + (SL)*8192; \
  int u2=(T)+2; if(u2>NT2-1)u2=NT2-1; size_t o2=(size_t)u2*32; \
  _Pragma("unroll") for (int m=0;m<4;++m) aQ[m] = *(const bf16x8*)(aS + aRd + m*1024); \
  _Pragma("unroll") for (int n=0;n<4;++n) bR[n] = *(const bf16x8*)(bS + bRd + n*1024); \
  GLOAD(aSrc0+o2, (SP)*16384); \
  GLOAD(aSrc1+o2, (SP)*16384 + 8192); \
  GLOAD(bSrc +o2, 49152 + (SP)*8192); \
  PHASE_MID; \
  _Pragma("unroll") for (int m=0;m<4;++m){ _Pragma("unroll") for (int n=0;n<4;++n) \
    acc[m][n] = __builtin_amdgcn_mfma_f32_16x16x32_bf16(aQ[m], bR[n], acc[m][n], 0,0,0); } \
  __builtin_amdgcn_s_setprio(0); \
  asm volatile("s_waitcnt vmcnt(3)" ::: "memory"); \
  __builtin_amdgcn_s_barrier(); }while(0)

__global__ __launch_bounds__(512, 4) void k_gemm2b(const unsigned short* __restrict__ A,
                                                   const unsigned short* __restrict__ Bt,
                                                   float* __restrict__ C,
                                                   const float* __restrict__ bias,
                                                   int M, int N, int NTN, int NWG){
  __shared__ char smem[73728];   // A 3x16KB | B 3x8KB
  int wg = blockIdx.x;
  int cpx = NWG >> 3;
  int swz = (wg & 7)*cpx + (wg >> 3);
  int bm = swz / NTN, bn = swz - bm*NTN;
  int m0 = bm << 8, n0 = bn << 7;

  int tid = threadIdx.x;
  int w = tid >> 6, lane = tid & 63;
  int r = lane & 15, g4 = lane >> 4;
  int wr = w >> 1, wc = w & 1;

  int seg = g4 ^ (((r >> 3) & 1) << 1);
  int aRd = (wr*64 + r)*64 + seg*16;
  int bRd = (wc*64 + r)*64 + seg*16;

  int srow = tid >> 2;
  int gsw  = (tid & 3) ^ (((tid >> 5) & 1) << 1);
  const unsigned short* aSrc0 = A  + (size_t)(m0 + srow)*GK + gsw*8;
  const unsigned short* aSrc1 = aSrc0 + (size_t)128*GK;
  const unsigned short* bSrc  = Bt + (size_t)(n0 + srow)*GK + gsw*8;

  const f32x4 fz = {0.f,0.f,0.f,0.f};
  f32x4 acc[4][4];
  #pragma unroll
  for (int m=0;m<4;++m)
    #pragma unroll
    for (int n=0;n<4;++n) acc[m][n] = fz;
  bf16x8 aQ[4], bR[4];

  // prologue: t0 -> slot0, t1 -> slot1
  GLOAD(aSrc0+ 0, 0);     GLOAD(aSrc1+ 0, 8192);       GLOAD(bSrc+ 0, 49152);
  GLOAD(aSrc0+32, 16384); GLOAD(aSrc1+32, 16384+8192); GLOAD(bSrc+32, 49152+8192);
  asm volatile("s_waitcnt vmcnt(3)" ::: "memory");
  __builtin_amdgcn_s_barrier();

  #pragma unroll 1
  for (int tt=0; tt<NT2; tt+=3){
    TILE2(tt,   0, 2);
    TILE2(tt+1, 1, 0);
    TILE2(tt+2, 2, 1);
  }
  asm volatile("s_waitcnt vmcnt(0)" ::: "memory");

  #pragma unroll
  for (int mi=0;mi<4;++mi){
    #pragma unroll
    for (int ni=0;ni<4;++ni){
      int col = n0 + wc*64 + ni*16 + r;
      float bb = bias ? bias[col] : 0.f;
      #pragma unroll
      for (int q=0;q<4;++q){
        int row = m0 + wr*64 + mi*16 + g4*4 + q;
        C[(size_t)row*N + col] = acc[mi][ni][q] + bb;
      }
    }
  }
}

// ---------------- dRoFE + attention, head-major qkv ----------------
__global__ __launch_bounds__(256) void k_attn(const unsigned short* __restrict__ qkv,
                                              const float* __restrict__ demo,
                                              const float* __restrict__ cs,
                                              const float* __restrict__ sn,
                                              unsigned short* __restrict__ out){
  __shared__ float kl[PPB][SEQ][68];
  __shared__ float s_cs[SEQ*DH], s_sn[SEQ*DH];
  int tid = threadIdx.x;
  for (int t=tid; t<SEQ*DH; t+=256){ s_cs[t]=cs[t]; s_sn[t]=sn[t]; }

  int pr = tid / 9, i = tid - pr*9;
  int pair = blockIdx.x*PPB + pr;
  bool act = (pr < PPB) && (pair < NPAIR);
  int b = 0, h = 0; float age = 0.f, gen = 0.f;
  const unsigned short* base = qkv;
  if (act){
    b = pair / HEADS; h = pair - b*HEADS;
    age = demo[2*b]; gen = demo[2*b+1];
    base = qkv + (size_t)pair*(SEQ*192);
  }
  __syncthreads();

  float qr[64];
  if (act){
    const u16x8* qp = (const u16x8*)(base + (size_t)i*192);
    const u16x8* kp = (const u16x8*)(base + (size_t)i*192 + 64);
    #pragma unroll
    for (int t8=0;t8<8;++t8){
      u16x8 qv = qp[t8], kv = kp[t8];
      #pragma unroll
      for (int e=0;e<8;e+=2){
        int d = t8*8+e;
        float c0=s_cs[i*64+d], s0=s_sn[i*64+d];
        float c1=s_cs[i*64+d+1], s1=s_sn[i*64+d+1];
        float q0=b2f(qv[e]), q1=b2f(qv[e+1]);
        qr[d]   = age*q0*c0 - gen*q1*s0;
        qr[d+1] = age*q1*c1 + gen*q0*s1;
        float k0=b2f(kv[e]), k1=b2f(kv[e+1]);
        kl[pr][i][d]   = age*k0*c0 - gen*k1*s0;
        kl[pr][i][d+1] = age*k1*c1 + gen*k0*s1;
      }
    }
  }
  __syncthreads();

  if (!act) return;

  float s[9]; float mx = -1e30f;
  #pragma unroll
  for (int j=0;j<9;++j){
    const float4* kr = (const float4*)(&kl[pr][j][0]);
    float acc = 0.f;
    #pragma unroll
    for (int d4=0;d4<16;++d4){
      float4 kv = kr[d4];
      acc += qr[d4*4]*kv.x + qr[d4*4+1]*kv.y + qr[d4*4+2]*kv.z + qr[d4*4+3]*kv.w;
    }
    s[j] = acc * 0.125f;
    mx = fmaxf(mx, s[j]);
  }
  float den = 0.f;
  #pragma unroll
  for (int j=0;j<9;++j){ s[j] = __expf(s[j]-mx); den += s[j]; }
  float inv = 1.f/den;

  float o[64];
  #pragma unroll
  for (int d=0;d<64;++d) o[d]=0.f;
  #pragma unroll
  for (int j=0;j<9;++j){
    float p = s[j]*inv;
    const u16x8* vp = (const u16x8*)(base + (size_t)j*192 + 128);
    #pragma unroll
    for (int t8=0;t8<8;++t8){
      u16x8 v = vp[t8];
      #pragma unroll
      for (int e=0;e<8;++e) o[t8*8+e] += p*b2f(v[e]);
    }
  }

  u16x8* op = (u16x8*)(out + (size_t)(b*SEQ+i)*CDIM + h*DH);
  #pragma unroll
  for (int t8=0;t8<8;++t8){
    u16x8 v;
    #pragma unroll
    for (int e=0;e<8;++e) v[e]=f2b(o[t8*8+e]);
    op[t8]=v;
  }
}

extern "C" void kernel_launch(void* const* d_in, const int* in_sizes, int n_in,
                              void* d_out, int out_size, void* d_ws, size_t ws_size,
                              hipStream_t stream){
  const float* x    = (const float*)d_in[0];
  const float* demo = (const float*)d_in[1];
  const float* Wq   = (const float*)d_in[2];
  const float* Wp   = (const float*)d_in[3];
  const float* bp   = (const float*)d_in[4];
  float* outp = (float*)d_out;

  char* wsb = (char*)d_ws;
  unsigned short* xb   = (unsigned short*)wsb;              // x bf16; reused as attn out
  unsigned short* Wq_t = (unsigned short*)(wsb + 56623104); // [2304][768]
  unsigned short* Wp_t = (unsigned short*)(wsb + 60162048); // [768][768]
  float* cs = (float*)(wsb + 61341696);
  float* sn = cs + SEQ*DH;
  unsigned short* qkv  = (unsigned short*)(wsb + 61346304); // head-major [49152][9][192]

  k_conv <<< MROWS*CDIM/1024, 256, 0, stream >>> (x, xb);
  k_tconv<<< CDIM*NQKV/256,  256, 0, stream >>> (Wq, Wq_t, CDIM, NQKV);
  k_tconv<<< CDIM*CDIM/256,  256, 0, stream >>> (Wp, Wp_t, CDIM, CDIM);
  k_table<<< 1, 576, 0, stream >>> (cs, sn);

  {
    int nwg = (MROWS/256)*(NQKV/256);   // 144*9 = 1296, %8==0
    k_gemm8p<0><<< nwg, 512, 0, stream >>>
        (xb, Wq_t, qkv, nullptr, MROWS, NQKV, NQKV/256, nwg);
  }

  k_attn <<< (NPAIR + PPB - 1)/PPB, 256, 0, stream >>> (qkv, demo, cs, sn, xb);

  {
    int nwg = (MROWS/256)*(CDIM/128);   // 144*6 = 864, %8==0
    k_gemm2b<<< nwg, 512, 0, stream >>>
        (xb, Wp_t, outp, bp, MROWS, CDIM, CDIM/128, nwg);
  }
}